// Round 6
// baseline (3474.131 us; speedup 1.0000x reference)
//
#include <hip/hip_runtime.h>

#define CPG 8
#define NGRP 32
#define NB 16
#define HW 3136
#define HU 784       // float4 units per channel
#define HALF 392     // pairing stride: thread t handles float4 units t and t+392
#define N2 36
#define N3 120

typedef float vfloat4 __attribute__((ext_vector_type(4)));

__host__ __device__ constexpr int idx2(int i, int j) {
    return i * CPG - i * (i - 1) / 2 + (j - i);
}
__host__ __device__ constexpr int idx3(int a, int b, int c) {
    int base = 0;
    for (int t = 0; t < a; ++t) { int m = CPG - t; base += m * (m + 1) / 2; }
    for (int t = a; t < b; ++t) base += CPG - t;
    return base + (c - b);
}

// one broadcast ds_read_b128 (4 outputs' weights) amortized over 8 pixels (2 vfloat4)
#define ACCUM2(F, TA, TB) do {                                                 \
    const vfloat4 w = *reinterpret_cast<const vfloat4*>(&wt[(F)][0]);          \
    accA[0] += w.x * (TA); accB[0] += w.x * (TB);                              \
    accA[1] += w.y * (TA); accB[1] += w.y * (TB);                              \
    accA[2] += w.z * (TA); accB[2] += w.z * (TB);                              \
    accA[3] += w.w * (TA); accB[3] += w.w * (TB);                              \
} while (0)

// scheduler fence: prevents mass ds_read hoisting -> bounded register pressure
#define FENCE() __builtin_amdgcn_sched_barrier(0)

__global__ __launch_bounds__(392, 3) void hoaf_kernel(
    const float* __restrict__ x,
    const float* __restrict__ w1, const float* __restrict__ b1,
    const float* __restrict__ w2, const float* __restrict__ b2,
    const float* __restrict__ w3, const float* __restrict__ b3,
    float* __restrict__ out)
{
    // wt[f][0..4): weights for this block's 4 output channels; f 0-7 deg1,
    // 8-43 deg2, 44-163 deg3, 164 = summed bias
    __shared__ __align__(16) float wt[165][4];

    const int tid   = threadIdx.x;
    const int obase = (int)blockIdx.x * 4;   // output-channel split
    const int g     = blockIdx.y;            // block-uniform group
    const int b     = blockIdx.z;

    for (int idx = tid; idx < 165 * 4; idx += 392) {
        const int f = idx >> 2, o = idx & 3;
        const int ch = g * CPG + obase + o;
        float v;
        if (f < 8)        v = w1[ch * CPG + f];
        else if (f < 44)  v = w2[ch * N2 + (f - 8)];
        else if (f < 164) v = w3[ch * N3 + (f - 44)];
        else              v = b1[ch] + b2[ch] + b3[ch];
        wt[f][o] = v;
    }
    __syncthreads();

    const vfloat4 bias = *reinterpret_cast<const vfloat4*>(&wt[164][0]);

    const size_t base = ((size_t)(b * NGRP + g) * CPG) * HW;
    const vfloat4* x4 = (const vfloat4*)(x + base);
    vfloat4*       o4 = (vfloat4*)(out + base) + (size_t)obase * HU;

    const int q = tid;   // 0..391, single-shot (no pixel loop)

    vfloat4 xa[CPG], xb[CPG];
#pragma unroll
    for (int c = 0; c < CPG; ++c) {
        xa[c] = x4[(size_t)c * HU + q];
        xb[c] = x4[(size_t)c * HU + HALF + q];
    }

    vfloat4 accA[4], accB[4];
    accA[0] = {bias.x, bias.x, bias.x, bias.x};
    accA[1] = {bias.y, bias.y, bias.y, bias.y};
    accA[2] = {bias.z, bias.z, bias.z, bias.z};
    accA[3] = {bias.w, bias.w, bias.w, bias.w};
#pragma unroll
    for (int k = 0; k < 4; ++k) accB[k] = accA[k];

    // degree 1
#pragma unroll
    for (int k = 0; k < CPG; k += 2) {
        ACCUM2(k, xa[k], xb[k]);
        ACCUM2(k + 1, xa[k + 1], xb[k + 1]);
        FENCE();
    }

    // degree 2 & 3: pair product (i<=j) feeds triples (a<=i<=j)
#pragma unroll
    for (int i = 0; i < CPG; ++i) {
#pragma unroll
        for (int j = i; j < CPG; ++j) {
            const vfloat4 pa = xa[i] * xa[j];
            const vfloat4 pb = xb[i] * xb[j];
            ACCUM2(8 + idx2(i, j), pa, pb);
#pragma unroll
            for (int a = 0; a <= i; ++a) {
                const vfloat4 ta = xa[a] * pa;
                const vfloat4 tb = xb[a] * pb;
                ACCUM2(44 + idx3(a, i, j), ta, tb);
            }
            FENCE();
        }
    }

#pragma unroll
    for (int k = 0; k < 4; ++k) {
        o4[(size_t)k * HU + q]        = accA[k];
        o4[(size_t)k * HU + HALF + q] = accB[k];
    }
}

extern "C" void kernel_launch(void* const* d_in, const int* in_sizes, int n_in,
                              void* d_out, int out_size, void* d_ws, size_t ws_size,
                              hipStream_t stream) {
    const float* x  = (const float*)d_in[0];
    const float* w1 = (const float*)d_in[1];
    const float* b1 = (const float*)d_in[2];
    const float* w2 = (const float*)d_in[3];
    const float* b2 = (const float*)d_in[4];
    const float* w3 = (const float*)d_in[5];
    const float* b3 = (const float*)d_in[6];
    float* out = (float*)d_out;

    dim3 grid(2, NGRP, NB);   // (output split, group, batch)
    dim3 block(392);
    hoaf_kernel<<<grid, block, 0, stream>>>(x, w1, b1, w2, b2, w3, b3, out);
}

// Round 7
// 154.147 us; speedup vs baseline: 22.5377x; 22.5377x over previous
//
#include <hip/hip_runtime.h>

#define CPG 8
#define NGRP 32
#define NB 16
#define HW 3136
#define HU 784       // float4 units per channel image
#define N2 36
#define N3 120

typedef float vfloat4 __attribute__((ext_vector_type(4)));

__host__ __device__ constexpr int idx2(int i, int j) {
    return i * CPG - i * (i - 1) / 2 + (j - i);
}
__host__ __device__ constexpr int idx3(int a, int b, int c) {
    int base = 0;
    for (int t = 0; t < a; ++t) { int m = CPG - t; base += m * (m + 1) / 2; }
    for (int t = a; t < b; ++t) base += CPG - t;
    return base + (c - b);
}

__device__ inline vfloat4 splat4(float s) { return (vfloat4){s, s, s, s}; }

// feature T (vfloat4 = 4 pixels) x wt[F][0..8): two broadcast ds_read_b128 + 32 fmac
#define ACCUM(F, T) do {                                                       \
    const vfloat4 wa = *reinterpret_cast<const vfloat4*>(&wt[(F)][0]);         \
    const vfloat4 wb = *reinterpret_cast<const vfloat4*>(&wt[(F)][4]);         \
    acc[0] += wa.x * (T); acc[1] += wa.y * (T);                                \
    acc[2] += wa.z * (T); acc[3] += wa.w * (T);                                \
    acc[4] += wb.x * (T); acc[5] += wb.y * (T);                                \
    acc[6] += wb.z * (T); acc[7] += wb.w * (T);                                \
} while (0)

// scheduler fence: prevents mass ds_read hoisting -> bounded register pressure
#define FENCE() __builtin_amdgcn_sched_barrier(0)

__global__ __launch_bounds__(256, 3) void hoaf_kernel(
    const float* __restrict__ x,
    const float* __restrict__ w1, const float* __restrict__ b1,
    const float* __restrict__ w2, const float* __restrict__ b2,
    const float* __restrict__ w3, const float* __restrict__ b3,
    float* __restrict__ out)
{
    // wt[f][o]: f 0-7 deg1, 8-43 deg2, 44-163 deg3, 164 = summed bias
    __shared__ __align__(16) float wt[165][8];

    const int tid   = threadIdx.x;
    const int chunk = blockIdx.x;   // 0..3; chunk 3 is a 16-unit runt
    const int g     = blockIdx.y;   // block-uniform group
    const int b     = blockIdx.z;

    for (int idx = tid; idx < 165 * 8; idx += 256) {
        const int f = idx >> 3, o = idx & 7;
        const int ch = g * CPG + o;
        float v;
        if (f < 8)        v = w1[ch * CPG + f];
        else if (f < 44)  v = w2[ch * N2 + (f - 8)];
        else if (f < 164) v = w3[ch * N3 + (f - 44)];
        else              v = b1[ch] + b2[ch] + b3[ch];
        wt[f][o] = v;
    }
    __syncthreads();

    const int q = tid + chunk * 256;   // one body per thread
    if (q >= HU) return;

    const vfloat4 b_lo = *reinterpret_cast<const vfloat4*>(&wt[164][0]);
    const vfloat4 b_hi = *reinterpret_cast<const vfloat4*>(&wt[164][4]);

    const size_t base = ((size_t)(b * NGRP + g) * CPG) * HW;
    const vfloat4* x4 = (const vfloat4*)(x + base);
    vfloat4*       o4 = (vfloat4*)(out + base);

    vfloat4 xv[CPG];
#pragma unroll
    for (int c = 0; c < CPG; ++c) xv[c] = x4[(size_t)c * HU + q];

    vfloat4 acc[CPG];
    acc[0] = splat4(b_lo.x); acc[1] = splat4(b_lo.y);
    acc[2] = splat4(b_lo.z); acc[3] = splat4(b_lo.w);
    acc[4] = splat4(b_hi.x); acc[5] = splat4(b_hi.y);
    acc[6] = splat4(b_hi.z); acc[7] = splat4(b_hi.w);

    // degree 1, fenced every 2 features
#pragma unroll
    for (int k = 0; k < CPG; k += 2) {
        ACCUM(k, xv[k]);
        ACCUM(k + 1, xv[k + 1]);
        FENCE();
    }

    // degree 2 & 3: pair product (i<=j) feeds triples (a<=i<=j);
    // one fence per (i,j) group keeps <= ~10 weight b128s in flight
#pragma unroll
    for (int i = 0; i < CPG; ++i) {
#pragma unroll
        for (int j = i; j < CPG; ++j) {
            const vfloat4 p = xv[i] * xv[j];
            ACCUM(8 + idx2(i, j), p);
#pragma unroll
            for (int a = 0; a <= i; ++a) {
                const vfloat4 t = xv[a] * p;
                ACCUM(44 + idx3(a, i, j), t);
            }
            FENCE();
        }
    }

#pragma unroll
    for (int o = 0; o < CPG; ++o) o4[(size_t)o * HU + q] = acc[o];
}

extern "C" void kernel_launch(void* const* d_in, const int* in_sizes, int n_in,
                              void* d_out, int out_size, void* d_ws, size_t ws_size,
                              hipStream_t stream) {
    const float* x  = (const float*)d_in[0];
    const float* w1 = (const float*)d_in[1];
    const float* b1 = (const float*)d_in[2];
    const float* w2 = (const float*)d_in[3];
    const float* b2 = (const float*)d_in[4];
    const float* w3 = (const float*)d_in[5];
    const float* b3 = (const float*)d_in[6];
    float* out = (float*)d_out;

    dim3 grid(4, NGRP, NB);   // (pixel chunk, group, batch)
    dim3 block(256);
    hoaf_kernel<<<grid, block, 0, stream>>>(x, w1, b1, w2, b2, w3, b3, out);
}